// Round 1
// baseline (627.612 us; speedup 1.0000x reference)
//
#include <hip/hip_runtime.h>
#include <hip/hip_bf16.h>
#include <cstdint>

#define B_TOK 16384
#define HDIM  1024
#define HGATE 512
#define NPATH 8
#define THRV  0.1f
#define RESSCALE 512.0f
#define MAXROWS (2 * B_TOK + NPATH * 128)   // padded compact rows bound

typedef __bf16 bf16x8 __attribute__((ext_vector_type(8)));
typedef _Float16 f16x8 __attribute__((ext_vector_type(8)));
typedef float  f32x4  __attribute__((ext_vector_type(4)));
typedef unsigned short u16;

__device__ __forceinline__ u16 f2bf(float f) {
    uint32_t u = __float_as_uint(f);
    u += 0x7fff + ((u >> 16) & 1);   // RNE
    return (u16)(u >> 16);
}
__device__ __forceinline__ float bf2f(u16 v) {
    return __uint_as_float((uint32_t)v << 16);
}
union H16 { _Float16 h; u16 u; };
__device__ __forceinline__ u16 f2h(float f) { H16 t; t.h = (_Float16)f; return t.u; }
__device__ __forceinline__ float h2f(u16 b) { H16 t; t.u = b; return (float)t.h; }
__device__ __forceinline__ float silu_f(float a) {
    return a / (1.0f + expf(-a));
}
__device__ __forceinline__ f32x4 mfma_bf16(bf16x8 a, bf16x8 b, f32x4 c) {
    return __builtin_amdgcn_mfma_f32_16x16x32_bf16(a, b, c, 0, 0, 0);
}
__device__ __forceinline__ f32x4 mfma_f16(f16x8 a, f16x8 b, f32x4 c) {
    return __builtin_amdgcn_mfma_f32_16x16x32_f16(a, b, c, 0, 0, 0);
}
// async global->LDS 16B/lane; lds base must be wave-uniform (dest = base + lane*16)
__device__ __forceinline__ void async_lds16(const u16* g, u16* l) {
    __builtin_amdgcn_global_load_lds((const __attribute__((address_space(1))) uint32_t*)g,
                                     (__attribute__((address_space(3))) uint32_t*)l,
                                     16, 0, 0);
}

// ---------------- x -> bf16 (for paths) + f16 hi + f16 residual*512 (for gate) --------
__global__ void k_convert_x(const float* __restrict__ x, u16* __restrict__ xb,
                            u16* __restrict__ xh, u16* __restrict__ xl) {
    int i = (blockIdx.x * 256 + threadIdx.x) * 4;
    float4 v = *(const float4*)(x + i);
    float vv[4] = {v.x, v.y, v.z, v.w};
    u16 hb[4], hh[4], hl[4];
    #pragma unroll
    for (int c = 0; c < 4; c++) {
        hb[c] = f2bf(vv[c]);
        u16 hi = f2h(vv[c]);
        hh[c] = hi;
        hl[c] = f2h((vv[c] - h2f(hi)) * RESSCALE);
    }
    uint2 ob, oh, ol;
    ob.x = (uint32_t)hb[0] | ((uint32_t)hb[1] << 16);
    ob.y = (uint32_t)hb[2] | ((uint32_t)hb[3] << 16);
    oh.x = (uint32_t)hh[0] | ((uint32_t)hh[1] << 16);
    oh.y = (uint32_t)hh[2] | ((uint32_t)hh[3] << 16);
    ol.x = (uint32_t)hl[0] | ((uint32_t)hl[1] << 16);
    ol.y = (uint32_t)hl[2] | ((uint32_t)hl[3] << 16);
    *(uint2*)(xb + i) = ob;
    *(uint2*)(xh + i) = oh;
    *(uint2*)(xl + i) = ol;
}

// ---------------- W (P,H,H) fp32 -> WT (P,H,H) bf16, WT[p][d][h]=W[p][h][d] ----------------
__global__ void k_transpose_bf16(const float* __restrict__ W, u16* __restrict__ WT) {
    __shared__ float tile[32][33];
    int p = blockIdx.z;
    const float* Wp = W + (size_t)p * HDIM * HDIM;
    u16* WTp = WT + (size_t)p * HDIM * HDIM;
    int d0 = blockIdx.x * 32, h0 = blockIdx.y * 32;
    int tx = threadIdx.x, ty = threadIdx.y;  // (32,8)
    #pragma unroll
    for (int rr = 0; rr < 4; rr++) {
        int r = ty + rr * 8;
        tile[r][tx] = Wp[(size_t)(h0 + r) * HDIM + d0 + tx];
    }
    __syncthreads();
    #pragma unroll
    for (int rr = 0; rr < 4; rr++) {
        int r = ty + rr * 8;
        WTp[(size_t)(d0 + r) * HDIM + h0 + tx] = f2bf(tile[tx][r]);
    }
}

// ---------------- W1 (H,HGATE) fp32 -> W1hT/W1lT (HGATE,H) f16 hi / residual*512 --------
__global__ void k_split_w1(const float* __restrict__ W1, u16* __restrict__ WhT,
                           u16* __restrict__ WlT) {
    __shared__ float tile[32][33];
    int n0 = blockIdx.x * 32, k0 = blockIdx.y * 32;
    int tx = threadIdx.x, ty = threadIdx.y;  // (32,8)
    #pragma unroll
    for (int rr = 0; rr < 4; rr++) {
        int r = ty + rr * 8;
        tile[r][tx] = W1[(size_t)(k0 + r) * HGATE + n0 + tx];
    }
    __syncthreads();
    #pragma unroll
    for (int rr = 0; rr < 4; rr++) {
        int r = ty + rr * 8;
        float v = tile[tx][r];
        u16 hi = f2h(v);
        WhT[(size_t)(n0 + r) * HDIM + k0 + tx] = hi;
        WlT[(size_t)(n0 + r) * HDIM + k0 + tx] = f2h((v - h2f(hi)) * RESSCALE);
    }
}

// ---------------- gate GEMM via 3x f16 MFMA: h = silu(x @ W1 + b1) -------------------
// 2-phase double-buffered staging: issue next K-tile's global_load_lds before
// computing the current tile; one barrier per K-step (its vmcnt(0) drain overlaps
// with ds_read+MFMA). Grid is (m,n) so the 4 n-blocks of one m-panel share an XCD L2.
__global__ __launch_bounds__(256) void k_gate_mfma(const u16* __restrict__ Ah,
                                                   const u16* __restrict__ Al,
                                                   const u16* __restrict__ BhT,
                                                   const u16* __restrict__ BlT,
                                                   const float* __restrict__ b1,
                                                   float* __restrict__ Hout) {
    __shared__ __align__(16) u16 smem[32768];  // 64KB: 2 buffers x 4 tiles of 128x32 f16
    int t = threadIdx.x;
    int m0 = blockIdx.x * 128, n0 = blockIdx.y * 128;
    int wave = t >> 6, lane = t & 63;
    int quad = lane >> 4, l16 = lane & 15;
    int wr = (wave >> 1) * 64, wc = (wave & 1) * 64;
    f32x4 acc[4][4] = {};
    f32x4 accm[4][4] = {};
    union UV { uint4 u; f16x8 v; };
    int c8 = (t & 3) * 8;
    int rb = t >> 2;
    int wb = wave * 512;   // wave-uniform LDS base (u16 elems) for async staging

    const u16* pAh0 = Ah + (size_t)(m0 + rb) * HDIM + c8;
    const u16* pAh1 = Ah + (size_t)(m0 + 64 + rb) * HDIM + c8;
    const u16* pAl0 = Al + (size_t)(m0 + rb) * HDIM + c8;
    const u16* pAl1 = Al + (size_t)(m0 + 64 + rb) * HDIM + c8;
    const u16* pBh0 = BhT + (size_t)(n0 + rb) * HDIM + c8;
    const u16* pBh1 = BhT + (size_t)(n0 + 64 + rb) * HDIM + c8;
    const u16* pBl0 = BlT + (size_t)(n0 + rb) * HDIM + c8;
    const u16* pBl1 = BlT + (size_t)(n0 + 64 + rb) * HDIM + c8;

    auto stage = [&](int buf, int kt) {
        u16* s = smem + buf * 16384;
        int ko = kt * 32;
        async_lds16(pAh0 + ko, s + wb);
        async_lds16(pAh1 + ko, s + 2048 + wb);
        async_lds16(pAl0 + ko, s + 4096 + wb);
        async_lds16(pAl1 + ko, s + 6144 + wb);
        async_lds16(pBh0 + ko, s + 8192 + wb);
        async_lds16(pBh1 + ko, s + 10240 + wb);
        async_lds16(pBl0 + ko, s + 12288 + wb);
        async_lds16(pBl1 + ko, s + 14336 + wb);
    };

    stage(0, 0);
    __syncthreads();   // drain prologue loads (compiler emits vmcnt(0) before barrier)
    int cur = 0;
    for (int kt = 0; kt < HDIM / 32; kt++) {
        if (kt + 1 < HDIM / 32) stage(cur ^ 1, kt + 1);   // in flight during compute
        u16* s = smem + cur * 16384;
        u16* lAh = s;
        u16* lAl = s + 4096;
        u16* lBh = s + 8192;
        u16* lBl = s + 12288;
        f16x8 avh[4], avl[4], bvh[4], bvl[4];
        #pragma unroll
        for (int i = 0; i < 4; i++) {
            UV u0; u0.u = *(uint4*)(lAh + ((wr + i * 16 + l16) * 32 + quad * 8));
            avh[i] = u0.v;
            UV u1; u1.u = *(uint4*)(lAl + ((wr + i * 16 + l16) * 32 + quad * 8));
            avl[i] = u1.v;
            UV u2; u2.u = *(uint4*)(lBh + ((wc + i * 16 + l16) * 32 + quad * 8));
            bvh[i] = u2.v;
            UV u3; u3.u = *(uint4*)(lBl + ((wc + i * 16 + l16) * 32 + quad * 8));
            bvl[i] = u3.v;
        }
        #pragma unroll
        for (int i = 0; i < 4; i++)
            #pragma unroll
            for (int j = 0; j < 4; j++) {
                acc[i][j]  = mfma_f16(avh[i], bvh[j], acc[i][j]);
                accm[i][j] = mfma_f16(avh[i], bvl[j], accm[i][j]);
                accm[i][j] = mfma_f16(avl[i], bvh[j], accm[i][j]);
            }
        __syncthreads();   // drains this iter's staged loads; readers done -> safe reuse
        cur ^= 1;
    }
    // epilogue: silu(acc + accm/512 + bias) -> Hout fp32, via LDS bounce in 64-row halves
    const float inv_s = 1.0f / RESSCALE;
    float* smf = (float*)smem;  // 64x128 fp32 = 32KB
    #pragma unroll
    for (int half = 0; half < 2; half++) {
        if ((wave >> 1) == half) {
            #pragma unroll
            for (int j = 0; j < 4; j++) {
                float bj = b1[n0 + wc + j * 16 + l16];
                #pragma unroll
                for (int i = 0; i < 4; i++)
                    #pragma unroll
                    for (int r = 0; r < 4; r++) {
                        int rrow = i * 16 + quad * 4 + r;
                        float v = acc[i][j][r] + accm[i][j][r] * inv_s + bj;
                        smf[rrow * 128 + wc + j * 16 + l16] = silu_f(v);
                    }
            }
        }
        __syncthreads();
        #pragma unroll
        for (int it = 0; it < 8; it++) {
            int c = t + it * 256;
            int row = c >> 5, c4 = (c & 31) * 4;
            *(float4*)(Hout + (size_t)(m0 + half * 64 + row) * HGATE + n0 + c4) =
                *(float4*)(smf + c * 4);
        }
        __syncthreads();
    }
}

// ---------------- per-token: logits -> softmax -> top2/threshold + list build --------
__global__ __launch_bounds__(256) void k_gate_topk(const float* __restrict__ Hin,
                                                   const float* __restrict__ W2,
                                                   const float* __restrict__ b2,
                                                   float* __restrict__ gate_out,
                                                   float* __restrict__ wnorm,
                                                   int* __restrict__ counts,
                                                   int* __restrict__ tokens,
                                                   uint32_t* __restrict__ slots) {
    __shared__ float w2t[NPATH * HGATE];
    __shared__ int cnt[NPATH];
    __shared__ int baseS[NPATH];
    __shared__ unsigned short tloc[NPATH][64];
    __shared__ uint32_t sloc[64][2];
    int t = threadIdx.x;
    #pragma unroll
    for (int j = 0; j < 16; j++) {
        int i = t + j * 256;
        w2t[(i & 7) * HGATE + (i >> 3)] = W2[i];
    }
    if (t < NPATH) cnt[t] = 0;
    __syncthreads();
    int wave = t >> 6, lane = t & 63;
    #pragma unroll 1
    for (int it = 0; it < 16; it++) {
        int tl = wave * 16 + it;
        int token = blockIdx.x * 64 + tl;
        const float* hrow = Hin + (size_t)token * HGATE;
        float hv[8];
        {
            float4 h0 = *(const float4*)(hrow + lane * 8);
            float4 h1 = *(const float4*)(hrow + lane * 8 + 4);
            hv[0] = h0.x; hv[1] = h0.y; hv[2] = h0.z; hv[3] = h0.w;
            hv[4] = h1.x; hv[5] = h1.y; hv[6] = h1.z; hv[7] = h1.w;
        }
        float logit[8];
        #pragma unroll
        for (int p = 0; p < 8; p++) {
            float s = 0.0f;
            #pragma unroll
            for (int kk = 0; kk < 8; kk++) s += hv[kk] * w2t[p * HGATE + lane * 8 + kk];
            #pragma unroll
            for (int off = 32; off >= 1; off >>= 1) s += __shfl_xor(s, off);
            logit[p] = s + b2[p];
        }
        float mx = logit[0];
        #pragma unroll
        for (int p = 1; p < 8; p++) mx = fmaxf(mx, logit[p]);
        float pr[8], sum = 0.0f;
        #pragma unroll
        for (int p = 0; p < 8; p++) { pr[p] = expf(logit[p] - mx); sum += pr[p]; }
        float inv = 1.0f / sum;
        #pragma unroll
        for (int p = 0; p < 8; p++) pr[p] *= inv;
        // top-2, ties -> lowest index (matches lax.top_k)
        int i0 = 0; float v0 = pr[0];
        #pragma unroll
        for (int p = 1; p < 8; p++) { if (pr[p] > v0) { v0 = pr[p]; i0 = p; } }
        int i1 = -1; float v1 = -1.0f;
        #pragma unroll
        for (int p = 0; p < 8; p++) { if (p != i0 && pr[p] > v1) { v1 = pr[p]; i1 = p; } }
        float w0 = (v0 > THRV) ? v0 : 0.0f;
        float w1 = (v1 > THRV) ? v1 : 0.0f;
        float total = w0 + w1;
        float invden = (total > 0.0f) ? (1.0f / total) : 1.0f;
        if (lane < 8) {
            float prl = pr[0];
            #pragma unroll
            for (int p = 1; p < 8; p++) prl = (lane == p) ? pr[p] : prl;
            float wl = 0.0f;
            if (lane == i0) wl = w0 * invden;
            if (lane == i1) wl = w1 * invden;
            gate_out[(size_t)token * 8 + lane] = prl;
            wnorm[(size_t)token * 8 + lane] = wl;
        }
        if (lane == 0) {
            uint32_t e0 = 0xFFFFFFFFu, e1 = 0xFFFFFFFFu;
            if (w0 > 0.0f) {
                int j0 = atomicAdd(&cnt[i0], 1);
                tloc[i0][j0] = (unsigned short)tl;
                e0 = ((uint32_t)i0 << 16) | (uint32_t)j0;
            }
            if (w1 > 0.0f) {
                int j1 = atomicAdd(&cnt[i1], 1);
                tloc[i1][j1] = (unsigned short)tl;
                e1 = ((uint32_t)i1 << 16) | (uint32_t)j1;
            }
            sloc[tl][0] = e0; sloc[tl][1] = e1;
        }
    }
    __syncthreads();
    if (t < NPATH) baseS[t] = atomicAdd(&counts[t], cnt[t]);
    __syncthreads();
    for (int p = 0; p < NPATH; p++) {
        int n = cnt[p], b = baseS[p];
        for (int j = t; j < n; j += 256)
            tokens[p * B_TOK + b + j] = blockIdx.x * 64 + tloc[p][j];
    }
    if (t < 64) {
        #pragma unroll
        for (int s = 0; s < 2; s++) {
            uint32_t e = sloc[t][s];
            if (e != 0xFFFFFFFFu) {
                int p = e >> 16;
                int j = (int)(e & 0xFFFFu) + baseS[p];
                e = ((uint32_t)p << 16) | (uint32_t)j;
            }
            slots[(size_t)(blockIdx.x * 64 + t) * 2 + s] = e;
        }
    }
}

// ---------------- padded prefix offsets ----------------
__global__ void k_prefix(const int* __restrict__ counts, int* __restrict__ poffs) {
    if (threadIdx.x == 0) {
        int o = 0; poffs[0] = 0;
        for (int p = 0; p < NPATH; p++) {
            o += ((counts[p] + 127) >> 7) << 7;
            poffs[p + 1] = o;
        }
    }
}

// ---------------- path GEMM 1 (gather): hid[compact] = bf16(silu(x[tok] @ Wp + bp)) ----
// 2-phase double-buffered; grid (m,n,p) so all n-blocks of one m-panel share an XCD L2.
__global__ __launch_bounds__(256) void k_path1(const u16* __restrict__ A,
                                               const u16* __restrict__ WT,
                                               const float* __restrict__ pb,
                                               u16* __restrict__ hid,
                                               const int* __restrict__ counts,
                                               const int* __restrict__ tokens,
                                               const int* __restrict__ poffs) {
    int p = blockIdx.z;
    int count = counts[p];
    int m0 = blockIdx.x * 128;
    if (m0 >= count) return;
    int n0 = blockIdx.y * 128;
    int base = poffs[p];
    const u16* BT = WT + (size_t)p * HDIM * HDIM;
    const float* bias = pb + (size_t)p * HDIM;

    __shared__ __align__(16) u16 smem[16384];  // 32KB: 2 buffers x (128x32 A + 128x32 B)
    __shared__ int idx[128];
    int t = threadIdx.x;
    if (t < 128) {
        int j = m0 + t; if (j > count - 1) j = count - 1;
        idx[t] = tokens[p * B_TOK + j];
    }
    __syncthreads();
    int rowA0 = idx[t >> 2], rowA1 = idx[64 + (t >> 2)];
    int wave = t >> 6, lane = t & 63;
    int quad = lane >> 4, l16 = lane & 15;
    int wr = (wave >> 1) * 64, wc = (wave & 1) * 64;
    f32x4 acc[4][4] = {};
    union UV { uint4 u; bf16x8 v; };
    int c8 = (t & 3) * 8;
    int rb = t >> 2;
    int wb = wave * 512;

    const u16* pA0 = A + (size_t)rowA0 * HDIM + c8;
    const u16* pA1 = A + (size_t)rowA1 * HDIM + c8;
    const u16* pB0 = BT + (size_t)(n0 + rb) * HDIM + c8;
    const u16* pB1 = BT + (size_t)(n0 + 64 + rb) * HDIM + c8;

    auto stage = [&](int buf, int kt) {
        u16* s = smem + buf * 8192;
        int ko = kt * 32;
        async_lds16(pA0 + ko, s + wb);
        async_lds16(pA1 + ko, s + 2048 + wb);
        async_lds16(pB0 + ko, s + 4096 + wb);
        async_lds16(pB1 + ko, s + 6144 + wb);
    };

    stage(0, 0);
    __syncthreads();
    int cur = 0;
    for (int kt = 0; kt < HDIM / 32; kt++) {
        if (kt + 1 < HDIM / 32) stage(cur ^ 1, kt + 1);
        u16* lA = smem + cur * 8192;
        u16* lB = lA + 4096;
        bf16x8 av[4], bv[4];
        #pragma unroll
        for (int i = 0; i < 4; i++) {
            UV ua; ua.u = *(uint4*)(lA + ((wr + i * 16 + l16) * 32 + quad * 8));
            av[i] = ua.v;
            UV ub; ub.u = *(uint4*)(lB + ((wc + i * 16 + l16) * 32 + quad * 8));
            bv[i] = ub.v;
        }
        #pragma unroll
        for (int i = 0; i < 4; i++)
            #pragma unroll
            for (int j = 0; j < 4; j++)
                acc[i][j] = mfma_bf16(av[i], bv[j], acc[i][j]);
        __syncthreads();
        cur ^= 1;
    }
    #pragma unroll
    for (int j = 0; j < 4; j++) {
        float bj = bias[n0 + wc + j * 16 + l16];
        #pragma unroll
        for (int i = 0; i < 4; i++)
            #pragma unroll
            for (int r = 0; r < 4; r++) {
                int rrow = wr + i * 16 + quad * 4 + r;
                smem[rrow * 128 + wc + j * 16 + l16] = f2bf(silu_f(acc[i][j][r] + bj));
            }
    }
    __syncthreads();
    #pragma unroll
    for (int it = 0; it < 8; it++) {
        int c = t + it * 256;
        int row = c >> 4, cc = (c & 15) * 8;
        *(uint4*)(hid + (size_t)(base + m0 + row) * HDIM + n0 + cc) = *(uint4*)(smem + c * 8);
    }
}

// ---------------- path GEMM 2 (compact): pcomp = bf16(wnorm * (hid @ projWp)) ----------
__global__ __launch_bounds__(256) void k_path2(const u16* __restrict__ hid,
                                               const u16* __restrict__ WT,
                                               const float* __restrict__ wnorm,
                                               u16* __restrict__ pcomp,
                                               const int* __restrict__ counts,
                                               const int* __restrict__ tokens,
                                               const int* __restrict__ poffs) {
    int p = blockIdx.z;
    int count = counts[p];
    int m0 = blockIdx.x * 128;
    if (m0 >= count) return;
    int n0 = blockIdx.y * 128;
    int base = poffs[p];
    const u16* A = hid + (size_t)base * HDIM;
    const u16* BT = WT + (size_t)p * HDIM * HDIM;

    __shared__ __align__(16) u16 smem[16384];  // 32KB: 2 buffers x (A + B)
    __shared__ float wv[128];
    int t = threadIdx.x;
    if (t < 128) {
        int j = m0 + t; if (j > count - 1) j = count - 1;
        int tok = tokens[p * B_TOK + j];
        wv[t] = wnorm[(size_t)tok * NPATH + p];
    }
    int wave = t >> 6, lane = t & 63;
    int quad = lane >> 4, l16 = lane & 15;
    int wr = (wave >> 1) * 64, wc = (wave & 1) * 64;
    f32x4 acc[4][4] = {};
    union UV { uint4 u; bf16x8 v; };
    int c8 = (t & 3) * 8;
    int rb = t >> 2;
    int wb = wave * 512;

    const u16* pA0 = A + (size_t)(m0 + rb) * HDIM + c8;
    const u16* pA1 = A + (size_t)(m0 + 64 + rb) * HDIM + c8;
    const u16* pB0 = BT + (size_t)(n0 + rb) * HDIM + c8;
    const u16* pB1 = BT + (size_t)(n0 + 64 + rb) * HDIM + c8;

    auto stage = [&](int buf, int kt) {
        u16* s = smem + buf * 8192;
        int ko = kt * 32;
        async_lds16(pA0 + ko, s + wb);
        async_lds16(pA1 + ko, s + 2048 + wb);
        async_lds16(pB0 + ko, s + 4096 + wb);
        async_lds16(pB1 + ko, s + 6144 + wb);
    };

    stage(0, 0);
    __syncthreads();
    int cur = 0;
    for (int kt = 0; kt < HDIM / 32; kt++) {
        if (kt + 1 < HDIM / 32) stage(cur ^ 1, kt + 1);
        u16* lA = smem + cur * 8192;
        u16* lB = lA + 4096;
        bf16x8 av[4], bv[4];
        #pragma unroll
        for (int i = 0; i < 4; i++) {
            UV ua; ua.u = *(uint4*)(lA + ((wr + i * 16 + l16) * 32 + quad * 8));
            av[i] = ua.v;
            UV ub; ub.u = *(uint4*)(lB + ((wc + i * 16 + l16) * 32 + quad * 8));
            bv[i] = ub.v;
        }
        #pragma unroll
        for (int i = 0; i < 4; i++)
            #pragma unroll
            for (int j = 0; j < 4; j++)
                acc[i][j] = mfma_bf16(av[i], bv[j], acc[i][j]);
        __syncthreads();
        cur ^= 1;
    }
    #pragma unroll
    for (int j = 0; j < 4; j++) {
        #pragma unroll
        for (int i = 0; i < 4; i++)
            #pragma unroll
            for (int r = 0; r < 4; r++) {
                int rrow = wr + i * 16 + quad * 4 + r;
                smem[rrow * 128 + wc + j * 16 + l16] = f2bf(wv[rrow] * acc[i][j][r]);
            }
    }
    __syncthreads();
    #pragma unroll
    for (int it = 0; it < 8; it++) {
        int c = t + it * 256;
        int row = c >> 4, cc = (c & 15) * 8;
        *(uint4*)(pcomp + (size_t)(base + m0 + row) * HDIM + n0 + cc) = *(uint4*)(smem + c * 8);
    }
}

// ---------------- final gather + blend ----------------
__global__ __launch_bounds__(256) void k_blend2(const float* __restrict__ x,
                                                const u16* __restrict__ pcomp,
                                                const uint32_t* __restrict__ slots,
                                                const int* __restrict__ poffs,
                                                const float* __restrict__ blendp,
                                                float* __restrict__ out) {
    int t = threadIdx.x, wave = t >> 6, lane = t & 63;
    int token = blockIdx.x * 4 + wave;
    float alpha = 1.0f / (1.0f + expf(-blendp[0]));
    float beta = 1.0f - alpha;
    uint32_t s0 = slots[(size_t)token * 2];
    uint32_t s1 = slots[(size_t)token * 2 + 1];
    bool f0 = (s0 != 0xFFFFFFFFu), f1 = (s1 != 0xFFFFFFFFu);
    size_t r0 = 0, r1 = 0;
    if (f0) { int p = s0 >> 16, j = s0 & 0xFFFF; r0 = (size_t)(poffs[p] + j) * HDIM; }
    if (f1) { int p = s1 >> 16, j = s1 & 0xFFFF; r1 = (size_t)(poffs[p] + j) * HDIM; }
    const float* xrow = x + (size_t)token * HDIM;
    float* orow = out + (size_t)token * HDIM;
    #pragma unroll
    for (int c = 0; c < 4; c++) {
        int col = c * 256 + lane * 4;
        float4 xv = *(const float4*)(xrow + col);
        float4 o;
        if (f0) {
            uint2 u0 = *(const uint2*)(pcomp + r0 + col);
            float a0 = bf2f(u0.x & 0xFFFF), a1 = bf2f(u0.x >> 16);
            float a2 = bf2f(u0.y & 0xFFFF), a3 = bf2f(u0.y >> 16);
            if (f1) {
                uint2 u1 = *(const uint2*)(pcomp + r1 + col);
                a0 += bf2f(u1.x & 0xFFFF); a1 += bf2f(u1.x >> 16);
                a2 += bf2f(u1.y & 0xFFFF); a3 += bf2f(u1.y >> 16);
            }
            o.x = alpha * a0 + beta * xv.x;
            o.y = alpha * a1 + beta * xv.y;
            o.z = alpha * a2 + beta * xv.z;
            o.w = alpha * a3 + beta * xv.w;
        } else {
            o = xv;
        }
        *(float4*)(orow + col) = o;
    }
}

extern "C" void kernel_launch(void* const* d_in, const int* in_sizes, int n_in,
                              void* d_out, int out_size, void* d_ws, size_t ws_size,
                              hipStream_t stream) {
    const float* x   = (const float*)d_in[0];
    const float* gw1 = (const float*)d_in[1];
    const float* gb1 = (const float*)d_in[2];
    const float* gw2 = (const float*)d_in[3];
    const float* gb2 = (const float*)d_in[4];
    const float* pw  = (const float*)d_in[5];
    const float* pb  = (const float*)d_in[6];
    const float* prw = (const float*)d_in[7];
    const float* blend = (const float*)d_in[8];
    float* out = (float*)d_out;
    float* gate_out = out + (size_t)B_TOK * HDIM;

    char* w = (char*)d_ws;
    size_t o = 0;
    u16* xb      = (u16*)(w + o);   o += (size_t)B_TOK * HDIM * 2;
    u16* pathWT  = (u16*)(w + o);   o += (size_t)NPATH * HDIM * HDIM * 2;
    u16* projWT  = (u16*)(w + o);   o += (size_t)NPATH * HDIM * HDIM * 2;
    u16* w1hT    = (u16*)(w + o);   o += (size_t)HGATE * HDIM * 2;
    u16* w1lT    = (u16*)(w + o);   o += (size_t)HGATE * HDIM * 2;
    // hbuf (fp32, used until topk) overlaid with pcomp (bf16, written after topk)
    size_t uni = o;
    float* hbuf  = (float*)(w + uni);
    u16* pcomp   = (u16*)(w + uni);
    size_t hbuf_sz  = (size_t)B_TOK * HGATE * 4;
    size_t pcomp_sz = (size_t)MAXROWS * HDIM * 2;
    o += (hbuf_sz > pcomp_sz ? hbuf_sz : pcomp_sz);
    // xh/xl (f16 hi+residual of x, dead after gate GEMM) overlaid with hid (written by path1)
    size_t uni2 = o;
    u16* xh16    = (u16*)(w + uni2);                           // B_TOK*HDIM*2
    u16* xl16    = (u16*)(w + uni2 + (size_t)B_TOK * HDIM * 2); // B_TOK*HDIM*2
    u16* hid     = (u16*)(w + uni2);
    o += (size_t)MAXROWS * HDIM * 2;   // 69.2MB >= 2 * 33.6MB
    float* wnorm = (float*)(w + o); o += (size_t)B_TOK * NPATH * 4;
    int* tokens  = (int*)(w + o);   o += (size_t)NPATH * B_TOK * 4;
    uint32_t* slots = (uint32_t*)(w + o); o += (size_t)B_TOK * 2 * 4;
    int* counts  = (int*)(w + o);   o += 64;
    int* poffs   = (int*)(w + o);   o += 64;

    hipMemsetAsync(counts, 0, NPATH * sizeof(int), stream);
    k_convert_x<<<dim3((B_TOK * HDIM) / 1024), dim3(256), 0, stream>>>(x, xb, xh16, xl16);
    k_split_w1<<<dim3(HGATE / 32, HDIM / 32), dim3(32, 8), 0, stream>>>(gw1, w1hT, w1lT);
    k_transpose_bf16<<<dim3(32, 32, 8), dim3(32, 8), 0, stream>>>(pw, pathWT);
    k_transpose_bf16<<<dim3(32, 32, 8), dim3(32, 8), 0, stream>>>(prw, projWT);
    k_gate_mfma<<<dim3(B_TOK / 128, HGATE / 128), dim3(256), 0, stream>>>(
        xh16, xl16, w1hT, w1lT, gb1, hbuf);
    k_gate_topk<<<dim3(B_TOK / 64), dim3(256), 0, stream>>>(hbuf, gw2, gb2, gate_out,
                                                            wnorm, counts, tokens, slots);
    k_prefix<<<dim3(1), dim3(64), 0, stream>>>(counts, poffs);
    k_path1<<<dim3(128, 8, 8), dim3(256), 0, stream>>>(xb, pathWT, pb, hid,
                                                       counts, tokens, poffs);
    k_path2<<<dim3(128, 8, 8), dim3(256), 0, stream>>>(hid, projWT, wnorm, pcomp,
                                                       counts, tokens, poffs);
    k_blend2<<<dim3(B_TOK / 4), dim3(256), 0, stream>>>(x, pcomp, slots, poffs, blend, out);
}

// Round 3
// 598.687 us; speedup vs baseline: 1.0483x; 1.0483x over previous
//
#include <hip/hip_runtime.h>
#include <hip/hip_bf16.h>
#include <cstdint>

#define B_TOK 16384
#define HDIM  1024
#define HGATE 512
#define NPATH 8
#define THRV  0.1f
#define RESSCALE 512.0f
#define MAXROWS (2 * B_TOK + NPATH * 128)   // padded compact rows bound

typedef __bf16 bf16x8 __attribute__((ext_vector_type(8)));
typedef _Float16 f16x8 __attribute__((ext_vector_type(8)));
typedef float  f32x4  __attribute__((ext_vector_type(4)));
typedef unsigned short u16;

__device__ __forceinline__ u16 f2bf(float f) {
    uint32_t u = __float_as_uint(f);
    u += 0x7fff + ((u >> 16) & 1);   // RNE
    return (u16)(u >> 16);
}
__device__ __forceinline__ float bf2f(u16 v) {
    return __uint_as_float((uint32_t)v << 16);
}
union H16 { _Float16 h; u16 u; };
__device__ __forceinline__ u16 f2h(float f) { H16 t; t.h = (_Float16)f; return t.u; }
__device__ __forceinline__ float h2f(u16 b) { H16 t; t.u = b; return (float)t.h; }
__device__ __forceinline__ float silu_f(float a) {
    return a / (1.0f + expf(-a));
}
__device__ __forceinline__ f32x4 mfma_bf16(bf16x8 a, bf16x8 b, f32x4 c) {
    return __builtin_amdgcn_mfma_f32_16x16x32_bf16(a, b, c, 0, 0, 0);
}
__device__ __forceinline__ f32x4 mfma_f16(f16x8 a, f16x8 b, f32x4 c) {
    return __builtin_amdgcn_mfma_f32_16x16x32_f16(a, b, c, 0, 0, 0);
}
// async global->LDS 16B/lane; lds base must be wave-uniform (dest = base + lane*16)
__device__ __forceinline__ void async_lds16(const u16* g, u16* l) {
    __builtin_amdgcn_global_load_lds((const __attribute__((address_space(1))) uint32_t*)g,
                                     (__attribute__((address_space(3))) uint32_t*)l,
                                     16, 0, 0);
}

// Pipeline sync points: asm memory clobber = compiler fence (a bare
// __builtin_amdgcn_s_barrier has NO fence -> LDS reads could be hoisted past it).
#define PIPE_WAIT_BARRIER(N)                                             \
    do {                                                                 \
        asm volatile("s_waitcnt vmcnt(" #N ")\n\ts_barrier" ::: "memory"); \
        __builtin_amdgcn_sched_barrier(0);                               \
    } while (0)
#define PIPE_BARRIER() asm volatile("s_barrier" ::: "memory")

// LDS tile geometry: [128 rows][32 u16] = 64B rows = 4x 16B chunks.
// Linear dest (global_load_lds writes base+lane*16) => swizzle is applied on the
// GLOBAL SOURCE chunk index (rule 21: both-sides-or-neither): LDS[r][c] holds
// global chunk c ^ ((r>>1)&3). Fragment read applies the same XOR => read banks
// (16r + 4(quad^((r>>1)&3))) mod 32 cover all bank-quads 2x = conflict-free.
#define SWZ(r) (((r) >> 1) & 3)

// ---------------- x -> bf16 (for paths) + f16 hi + f16 residual*512 (for gate) --------
__global__ void k_convert_x(const float* __restrict__ x, u16* __restrict__ xb,
                            u16* __restrict__ xh, u16* __restrict__ xl) {
    int i = (blockIdx.x * 256 + threadIdx.x) * 4;
    float4 v = *(const float4*)(x + i);
    float vv[4] = {v.x, v.y, v.z, v.w};
    u16 hb[4], hh[4], hl[4];
    #pragma unroll
    for (int c = 0; c < 4; c++) {
        hb[c] = f2bf(vv[c]);
        u16 hi = f2h(vv[c]);
        hh[c] = hi;
        hl[c] = f2h((vv[c] - h2f(hi)) * RESSCALE);
    }
    uint2 ob, oh, ol;
    ob.x = (uint32_t)hb[0] | ((uint32_t)hb[1] << 16);
    ob.y = (uint32_t)hb[2] | ((uint32_t)hb[3] << 16);
    oh.x = (uint32_t)hh[0] | ((uint32_t)hh[1] << 16);
    oh.y = (uint32_t)hh[2] | ((uint32_t)hh[3] << 16);
    ol.x = (uint32_t)hl[0] | ((uint32_t)hl[1] << 16);
    ol.y = (uint32_t)hl[2] | ((uint32_t)hl[3] << 16);
    *(uint2*)(xb + i) = ob;
    *(uint2*)(xh + i) = oh;
    *(uint2*)(xl + i) = ol;
}

// ---------------- W (P,H,H) fp32 -> WT (P,H,H) bf16, WT[p][d][h]=W[p][h][d] ----------------
__global__ void k_transpose_bf16(const float* __restrict__ W, u16* __restrict__ WT) {
    __shared__ float tile[32][33];
    int p = blockIdx.z;
    const float* Wp = W + (size_t)p * HDIM * HDIM;
    u16* WTp = WT + (size_t)p * HDIM * HDIM;
    int d0 = blockIdx.x * 32, h0 = blockIdx.y * 32;
    int tx = threadIdx.x, ty = threadIdx.y;  // (32,8)
    #pragma unroll
    for (int rr = 0; rr < 4; rr++) {
        int r = ty + rr * 8;
        tile[r][tx] = Wp[(size_t)(h0 + r) * HDIM + d0 + tx];
    }
    __syncthreads();
    #pragma unroll
    for (int rr = 0; rr < 4; rr++) {
        int r = ty + rr * 8;
        WTp[(size_t)(d0 + r) * HDIM + h0 + tx] = f2bf(tile[tx][r]);
    }
}

// ---------------- W1 (H,HGATE) fp32 -> W1hT/W1lT (HGATE,H) f16 hi / residual*512 --------
__global__ void k_split_w1(const float* __restrict__ W1, u16* __restrict__ WhT,
                           u16* __restrict__ WlT) {
    __shared__ float tile[32][33];
    int n0 = blockIdx.x * 32, k0 = blockIdx.y * 32;
    int tx = threadIdx.x, ty = threadIdx.y;  // (32,8)
    #pragma unroll
    for (int rr = 0; rr < 4; rr++) {
        int r = ty + rr * 8;
        tile[r][tx] = W1[(size_t)(k0 + r) * HGATE + n0 + tx];
    }
    __syncthreads();
    #pragma unroll
    for (int rr = 0; rr < 4; rr++) {
        int r = ty + rr * 8;
        float v = tile[tx][r];
        u16 hi = f2h(v);
        WhT[(size_t)(n0 + r) * HDIM + k0 + tx] = hi;
        WlT[(size_t)(n0 + r) * HDIM + k0 + tx] = f2h((v - h2f(hi)) * RESSCALE);
    }
}

// ---------------- gate GEMM via 3x f16 MFMA: h = silu(x @ W1 + b1) -------------------
// Counted-vmcnt 2-buffer pipeline: next stage's 8 loads stay in flight across the
// compute phase (wait vmcnt(8) = previous stage only). All syncs are fenced asm.
__global__ __launch_bounds__(256) void k_gate_mfma(const u16* __restrict__ Ah,
                                                   const u16* __restrict__ Al,
                                                   const u16* __restrict__ BhT,
                                                   const u16* __restrict__ BlT,
                                                   const float* __restrict__ b1,
                                                   float* __restrict__ Hout) {
    __shared__ __align__(16) u16 smem[32768];  // 64KB: 2 bufs x 4 tiles of 128x32 f16
    int t = threadIdx.x;
    int m0 = blockIdx.x * 128, n0 = blockIdx.y * 128;
    int wave = t >> 6, lane = t & 63;
    int quad = lane >> 4, l16 = lane & 15;
    int wr = (wave >> 1) * 64, wc = (wave & 1) * 64;
    f32x4 acc[4][4] = {};
    f32x4 accm[4][4] = {};
    union UV { uint4 u; f16x8 v; };
    int rb = t >> 2;
    int cs = ((t & 3) ^ SWZ(rb)) * 8;   // swizzled source chunk (u16 elems)
    int wb = wave * 512;                // wave-uniform LDS base (u16 elems)

    // swizzled fragment-read offsets (u16 elems)
    int offA[4], offB[4];
    #pragma unroll
    for (int i = 0; i < 4; i++) {
        int rA = wr + i * 16 + l16;
        offA[i] = rA * 32 + (quad ^ SWZ(rA)) * 8;
        int rB = wc + i * 16 + l16;
        offB[i] = rB * 32 + (quad ^ SWZ(rB)) * 8;
    }

    const u16* pAh0 = Ah + (size_t)(m0 + rb) * HDIM + cs;
    const u16* pAh1 = Ah + (size_t)(m0 + 64 + rb) * HDIM + cs;
    const u16* pAl0 = Al + (size_t)(m0 + rb) * HDIM + cs;
    const u16* pAl1 = Al + (size_t)(m0 + 64 + rb) * HDIM + cs;
    const u16* pBh0 = BhT + (size_t)(n0 + rb) * HDIM + cs;
    const u16* pBh1 = BhT + (size_t)(n0 + 64 + rb) * HDIM + cs;
    const u16* pBl0 = BlT + (size_t)(n0 + rb) * HDIM + cs;
    const u16* pBl1 = BlT + (size_t)(n0 + 64 + rb) * HDIM + cs;

    auto stage = [&](int buf, int kt) {
        u16* s = smem + buf * 16384;
        int ko = kt * 32;
        async_lds16(pAh0 + ko, s + wb);
        async_lds16(pAh1 + ko, s + 2048 + wb);
        async_lds16(pAl0 + ko, s + 4096 + wb);
        async_lds16(pAl1 + ko, s + 6144 + wb);
        async_lds16(pBh0 + ko, s + 8192 + wb);
        async_lds16(pBh1 + ko, s + 10240 + wb);
        async_lds16(pBl0 + ko, s + 12288 + wb);
        async_lds16(pBl1 + ko, s + 14336 + wb);
    };
    auto compute = [&](int buf) {
        u16* s = smem + buf * 16384;
        u16* lAh = s;
        u16* lAl = s + 4096;
        u16* lBh = s + 8192;
        u16* lBl = s + 12288;
        f16x8 avh[4], avl[4], bvh[4], bvl[4];
        #pragma unroll
        for (int i = 0; i < 4; i++) {
            UV u0; u0.u = *(uint4*)(lAh + offA[i]); avh[i] = u0.v;
            UV u1; u1.u = *(uint4*)(lAl + offA[i]); avl[i] = u1.v;
            UV u2; u2.u = *(uint4*)(lBh + offB[i]); bvh[i] = u2.v;
            UV u3; u3.u = *(uint4*)(lBl + offB[i]); bvl[i] = u3.v;
        }
        #pragma unroll
        for (int i = 0; i < 4; i++)
            #pragma unroll
            for (int j = 0; j < 4; j++) {
                acc[i][j]  = mfma_f16(avh[i], bvh[j], acc[i][j]);
                accm[i][j] = mfma_f16(avh[i], bvl[j], accm[i][j]);
                accm[i][j] = mfma_f16(avl[i], bvh[j], accm[i][j]);
            }
    };

    stage(0, 0);
    for (int kt = 0; kt < 31; kt++) {
        stage((kt + 1) & 1, kt + 1);   // stays in flight across compute
        PIPE_WAIT_BARRIER(8);          // stage(kt) landed in ALL waves' slices
        compute(kt & 1);
        PIPE_BARRIER();                // all reads done before buffer reuse
    }
    PIPE_WAIT_BARRIER(0);
    compute(1);                        // kt=31
    PIPE_BARRIER();

    // epilogue: silu(acc + accm/512 + bias) -> Hout fp32, via LDS bounce in 64-row halves
    const float inv_s = 1.0f / RESSCALE;
    float* smf = (float*)smem;  // 64x128 fp32 = 32KB
    #pragma unroll
    for (int half = 0; half < 2; half++) {
        if ((wave >> 1) == half) {
            #pragma unroll
            for (int j = 0; j < 4; j++) {
                float bj = b1[n0 + wc + j * 16 + l16];
                #pragma unroll
                for (int i = 0; i < 4; i++)
                    #pragma unroll
                    for (int r = 0; r < 4; r++) {
                        int rrow = i * 16 + quad * 4 + r;
                        float v = acc[i][j][r] + accm[i][j][r] * inv_s + bj;
                        smf[rrow * 128 + wc + j * 16 + l16] = silu_f(v);
                    }
            }
        }
        __syncthreads();
        #pragma unroll
        for (int it = 0; it < 8; it++) {
            int c = t + it * 256;
            int row = c >> 5, c4 = (c & 31) * 4;
            *(float4*)(Hout + (size_t)(m0 + half * 64 + row) * HGATE + n0 + c4) =
                *(float4*)(smf + c * 4);
        }
        __syncthreads();
    }
}

// ---------------- per-token: logits -> softmax -> top2/threshold + list build --------
__global__ __launch_bounds__(256) void k_gate_topk(const float* __restrict__ Hin,
                                                   const float* __restrict__ W2,
                                                   const float* __restrict__ b2,
                                                   float* __restrict__ gate_out,
                                                   float* __restrict__ wnorm,
                                                   int* __restrict__ counts,
                                                   int* __restrict__ tokens,
                                                   uint32_t* __restrict__ slots) {
    __shared__ float w2t[NPATH * HGATE];
    __shared__ int cnt[NPATH];
    __shared__ int baseS[NPATH];
    __shared__ unsigned short tloc[NPATH][64];
    __shared__ uint32_t sloc[64][2];
    int t = threadIdx.x;
    #pragma unroll
    for (int j = 0; j < 16; j++) {
        int i = t + j * 256;
        w2t[(i & 7) * HGATE + (i >> 3)] = W2[i];
    }
    if (t < NPATH) cnt[t] = 0;
    __syncthreads();
    int wave = t >> 6, lane = t & 63;
    #pragma unroll 1
    for (int it = 0; it < 16; it++) {
        int tl = wave * 16 + it;
        int token = blockIdx.x * 64 + tl;
        const float* hrow = Hin + (size_t)token * HGATE;
        float hv[8];
        {
            float4 h0 = *(const float4*)(hrow + lane * 8);
            float4 h1 = *(const float4*)(hrow + lane * 8 + 4);
            hv[0] = h0.x; hv[1] = h0.y; hv[2] = h0.z; hv[3] = h0.w;
            hv[4] = h1.x; hv[5] = h1.y; hv[6] = h1.z; hv[7] = h1.w;
        }
        float logit[8];
        #pragma unroll
        for (int p = 0; p < 8; p++) {
            float s = 0.0f;
            #pragma unroll
            for (int kk = 0; kk < 8; kk++) s += hv[kk] * w2t[p * HGATE + lane * 8 + kk];
            #pragma unroll
            for (int off = 32; off >= 1; off >>= 1) s += __shfl_xor(s, off);
            logit[p] = s + b2[p];
        }
        float mx = logit[0];
        #pragma unroll
        for (int p = 1; p < 8; p++) mx = fmaxf(mx, logit[p]);
        float pr[8], sum = 0.0f;
        #pragma unroll
        for (int p = 0; p < 8; p++) { pr[p] = expf(logit[p] - mx); sum += pr[p]; }
        float inv = 1.0f / sum;
        #pragma unroll
        for (int p = 0; p < 8; p++) pr[p] *= inv;
        // top-2, ties -> lowest index (matches lax.top_k)
        int i0 = 0; float v0 = pr[0];
        #pragma unroll
        for (int p = 1; p < 8; p++) { if (pr[p] > v0) { v0 = pr[p]; i0 = p; } }
        int i1 = -1; float v1 = -1.0f;
        #pragma unroll
        for (int p = 0; p < 8; p++) { if (p != i0 && pr[p] > v1) { v1 = pr[p]; i1 = p; } }
        float w0 = (v0 > THRV) ? v0 : 0.0f;
        float w1 = (v1 > THRV) ? v1 : 0.0f;
        float total = w0 + w1;
        float invden = (total > 0.0f) ? (1.0f / total) : 1.0f;
        if (lane < 8) {
            float prl = pr[0];
            #pragma unroll
            for (int p = 1; p < 8; p++) prl = (lane == p) ? pr[p] : prl;
            float wl = 0.0f;
            if (lane == i0) wl = w0 * invden;
            if (lane == i1) wl = w1 * invden;
            gate_out[(size_t)token * 8 + lane] = prl;
            wnorm[(size_t)token * 8 + lane] = wl;
        }
        if (lane == 0) {
            uint32_t e0 = 0xFFFFFFFFu, e1 = 0xFFFFFFFFu;
            if (w0 > 0.0f) {
                int j0 = atomicAdd(&cnt[i0], 1);
                tloc[i0][j0] = (unsigned short)tl;
                e0 = ((uint32_t)i0 << 16) | (uint32_t)j0;
            }
            if (w1 > 0.0f) {
                int j1 = atomicAdd(&cnt[i1], 1);
                tloc[i1][j1] = (unsigned short)tl;
                e1 = ((uint32_t)i1 << 16) | (uint32_t)j1;
            }
            sloc[tl][0] = e0; sloc[tl][1] = e1;
        }
    }
    __syncthreads();
    if (t < NPATH) baseS[t] = atomicAdd(&counts[t], cnt[t]);
    __syncthreads();
    for (int p = 0; p < NPATH; p++) {
        int n = cnt[p], b = baseS[p];
        for (int j = t; j < n; j += 256)
            tokens[p * B_TOK + b + j] = blockIdx.x * 64 + tloc[p][j];
    }
    if (t < 64) {
        #pragma unroll
        for (int s = 0; s < 2; s++) {
            uint32_t e = sloc[t][s];
            if (e != 0xFFFFFFFFu) {
                int p = e >> 16;
                int j = (int)(e & 0xFFFFu) + baseS[p];
                e = ((uint32_t)p << 16) | (uint32_t)j;
            }
            slots[(size_t)(blockIdx.x * 64 + t) * 2 + s] = e;
        }
    }
}

// ---------------- padded prefix offsets ----------------
__global__ void k_prefix(const int* __restrict__ counts, int* __restrict__ poffs) {
    if (threadIdx.x == 0) {
        int o = 0; poffs[0] = 0;
        for (int p = 0; p < NPATH; p++) {
            o += ((counts[p] + 127) >> 7) << 7;
            poffs[p + 1] = o;
        }
    }
}

// ---------------- path GEMM 1 (gather): hid[compact] = bf16(silu(x[tok] @ Wp + bp)) ----
// 3-buffer, prefetch-distance-2, counted-vmcnt pipeline (fenced asm syncs):
// each stage has ~2 full compute phases to cover gathered-row latency.
__global__ __launch_bounds__(256) void k_path1(const u16* __restrict__ A,
                                               const u16* __restrict__ WT,
                                               const float* __restrict__ pb,
                                               u16* __restrict__ hid,
                                               const int* __restrict__ counts,
                                               const int* __restrict__ tokens,
                                               const int* __restrict__ poffs) {
    int p = blockIdx.z;
    int count = counts[p];
    int m0 = blockIdx.x * 128;
    if (m0 >= count) return;
    int n0 = blockIdx.y * 128;
    int base = poffs[p];
    const u16* BT = WT + (size_t)p * HDIM * HDIM;
    const float* bias = pb + (size_t)p * HDIM;

    __shared__ __align__(16) u16 smem[24576];  // 48KB: 3 bufs x (A 8KB + B 8KB)
    __shared__ int idx[128];
    int t = threadIdx.x;
    if (t < 128) {
        int j = m0 + t; if (j > count - 1) j = count - 1;
        idx[t] = tokens[p * B_TOK + j];
    }
    __syncthreads();
    int rb = t >> 2;
    int rowA0 = idx[rb], rowA1 = idx[64 + rb];
    int wave = t >> 6, lane = t & 63;
    int quad = lane >> 4, l16 = lane & 15;
    int wr = (wave >> 1) * 64, wc = (wave & 1) * 64;
    f32x4 acc[4][4] = {};
    union UV { uint4 u; bf16x8 v; };
    int cs = ((t & 3) ^ SWZ(rb)) * 8;
    int wb = wave * 512;

    int offA[4], offB[4];
    #pragma unroll
    for (int i = 0; i < 4; i++) {
        int rA = wr + i * 16 + l16;
        offA[i] = rA * 32 + (quad ^ SWZ(rA)) * 8;
        int rB = wc + i * 16 + l16;
        offB[i] = rB * 32 + (quad ^ SWZ(rB)) * 8;
    }

    const u16* pA0 = A + (size_t)rowA0 * HDIM + cs;
    const u16* pA1 = A + (size_t)rowA1 * HDIM + cs;
    const u16* pB0 = BT + (size_t)(n0 + rb) * HDIM + cs;
    const u16* pB1 = BT + (size_t)(n0 + 64 + rb) * HDIM + cs;

    auto stage = [&](int buf, int kt) {
        u16* s = smem + buf * 8192;
        int ko = kt * 32;
        async_lds16(pA0 + ko, s + wb);
        async_lds16(pA1 + ko, s + 2048 + wb);
        async_lds16(pB0 + ko, s + 4096 + wb);
        async_lds16(pB1 + ko, s + 6144 + wb);
    };
    auto compute = [&](int buf) {
        u16* lA = smem + buf * 8192;
        u16* lB = lA + 4096;
        bf16x8 av[4], bv[4];
        #pragma unroll
        for (int i = 0; i < 4; i++) {
            UV ua; ua.u = *(uint4*)(lA + offA[i]); av[i] = ua.v;
            UV ub; ub.u = *(uint4*)(lB + offB[i]); bv[i] = ub.v;
        }
        #pragma unroll
        for (int i = 0; i < 4; i++)
            #pragma unroll
            for (int j = 0; j < 4; j++)
                acc[i][j] = mfma_bf16(av[i], bv[j], acc[i][j]);
    };

    stage(0, 0);
    stage(1, 1);
    for (int kt = 0; kt < 30; kt++) {
        stage((kt + 2) % 3, kt + 2);   // distance-2 prefetch
        PIPE_WAIT_BARRIER(8);          // stage(kt) landed everywhere; 8 newer in flight
        compute(kt % 3);
        PIPE_BARRIER();                // reads done before buffer reuse
    }
    PIPE_WAIT_BARRIER(4);
    compute(0);                        // kt=30 (30%3==0)
    PIPE_WAIT_BARRIER(0);
    compute(1);                        // kt=31 (31%3==1)
    PIPE_BARRIER();                    // epilogue overwrites buffers below

    #pragma unroll
    for (int j = 0; j < 4; j++) {
        float bj = bias[n0 + wc + j * 16 + l16];
        #pragma unroll
        for (int i = 0; i < 4; i++)
            #pragma unroll
            for (int r = 0; r < 4; r++) {
                int rrow = wr + i * 16 + quad * 4 + r;
                smem[rrow * 128 + wc + j * 16 + l16] = f2bf(silu_f(acc[i][j][r] + bj));
            }
    }
    __syncthreads();
    #pragma unroll
    for (int it = 0; it < 8; it++) {
        int c = t + it * 256;
        int row = c >> 4, cc = (c & 15) * 8;
        *(uint4*)(hid + (size_t)(base + m0 + row) * HDIM + n0 + cc) = *(uint4*)(smem + c * 8);
    }
}

// ---------------- path GEMM 2 (compact): pcomp = bf16(wnorm * (hid @ projWp)) ----------
__global__ __launch_bounds__(256) void k_path2(const u16* __restrict__ hid,
                                               const u16* __restrict__ WT,
                                               const float* __restrict__ wnorm,
                                               u16* __restrict__ pcomp,
                                               const int* __restrict__ counts,
                                               const int* __restrict__ tokens,
                                               const int* __restrict__ poffs) {
    int p = blockIdx.z;
    int count = counts[p];
    int m0 = blockIdx.x * 128;
    if (m0 >= count) return;
    int n0 = blockIdx.y * 128;
    int base = poffs[p];
    const u16* A = hid + (size_t)base * HDIM;
    const u16* BT = WT + (size_t)p * HDIM * HDIM;

    __shared__ __align__(16) u16 smem[24576];  // 48KB: 3 bufs x (A 8KB + B 8KB)
    __shared__ float wv[128];
    int t = threadIdx.x;
    if (t < 128) {
        int j = m0 + t; if (j > count - 1) j = count - 1;
        int tok = tokens[p * B_TOK + j];
        wv[t] = wnorm[(size_t)tok * NPATH + p];
    }
    __syncthreads();   // retire the wv load before the counted-vmcnt ledger starts
    int rb = t >> 2;
    int wave = t >> 6, lane = t & 63;
    int quad = lane >> 4, l16 = lane & 15;
    int wr = (wave >> 1) * 64, wc = (wave & 1) * 64;
    f32x4 acc[4][4] = {};
    union UV { uint4 u; bf16x8 v; };
    int cs = ((t & 3) ^ SWZ(rb)) * 8;
    int wb = wave * 512;

    int offA[4], offB[4];
    #pragma unroll
    for (int i = 0; i < 4; i++) {
        int rA = wr + i * 16 + l16;
        offA[i] = rA * 32 + (quad ^ SWZ(rA)) * 8;
        int rB = wc + i * 16 + l16;
        offB[i] = rB * 32 + (quad ^ SWZ(rB)) * 8;
    }

    const u16* pA0 = A + (size_t)(m0 + rb) * HDIM + cs;
    const u16* pA1 = A + (size_t)(m0 + 64 + rb) * HDIM + cs;
    const u16* pB0 = BT + (size_t)(n0 + rb) * HDIM + cs;
    const u16* pB1 = BT + (size_t)(n0 + 64 + rb) * HDIM + cs;

    auto stage = [&](int buf, int kt) {
        u16* s = smem + buf * 8192;
        int ko = kt * 32;
        async_lds16(pA0 + ko, s + wb);
        async_lds16(pA1 + ko, s + 2048 + wb);
        async_lds16(pB0 + ko, s + 4096 + wb);
        async_lds16(pB1 + ko, s + 6144 + wb);
    };
    auto compute = [&](int buf) {
        u16* lA = smem + buf * 8192;
        u16* lB = lA + 4096;
        bf16x8 av[4], bv[4];
        #pragma unroll
        for (int i = 0; i < 4; i++) {
            UV ua; ua.u = *(uint4*)(lA + offA[i]); av[i] = ua.v;
            UV ub; ub.u = *(uint4*)(lB + offB[i]); bv[i] = ub.v;
        }
        #pragma unroll
        for (int i = 0; i < 4; i++)
            #pragma unroll
            for (int j = 0; j < 4; j++)
                acc[i][j] = mfma_bf16(av[i], bv[j], acc[i][j]);
    };

    stage(0, 0);
    stage(1, 1);
    for (int kt = 0; kt < 30; kt++) {
        stage((kt + 2) % 3, kt + 2);
        PIPE_WAIT_BARRIER(8);
        compute(kt % 3);
        PIPE_BARRIER();
    }
    PIPE_WAIT_BARRIER(4);
    compute(0);
    PIPE_WAIT_BARRIER(0);
    compute(1);
    PIPE_BARRIER();

    #pragma unroll
    for (int j = 0; j < 4; j++) {
        #pragma unroll
        for (int i = 0; i < 4; i++)
            #pragma unroll
            for (int r = 0; r < 4; r++) {
                int rrow = wr + i * 16 + quad * 4 + r;
                smem[rrow * 128 + wc + j * 16 + l16] = f2bf(wv[rrow] * acc[i][j][r]);
            }
    }
    __syncthreads();
    #pragma unroll
    for (int it = 0; it < 8; it++) {
        int c = t + it * 256;
        int row = c >> 4, cc = (c & 15) * 8;
        *(uint4*)(pcomp + (size_t)(base + m0 + row) * HDIM + n0 + cc) = *(uint4*)(smem + c * 8);
    }
}

// ---------------- final gather + blend ----------------
__global__ __launch_bounds__(256) void k_blend2(const float* __restrict__ x,
                                                const u16* __restrict__ pcomp,
                                                const uint32_t* __restrict__ slots,
                                                const int* __restrict__ poffs,
                                                const float* __restrict__ blendp,
                                                float* __restrict__ out) {
    int t = threadIdx.x, wave = t >> 6, lane = t & 63;
    int token = blockIdx.x * 4 + wave;
    float alpha = 1.0f / (1.0f + expf(-blendp[0]));
    float beta = 1.0f - alpha;
    uint32_t s0 = slots[(size_t)token * 2];
    uint32_t s1 = slots[(size_t)token * 2 + 1];
    bool f0 = (s0 != 0xFFFFFFFFu), f1 = (s1 != 0xFFFFFFFFu);
    size_t r0 = 0, r1 = 0;
    if (f0) { int p = s0 >> 16, j = s0 & 0xFFFF; r0 = (size_t)(poffs[p] + j) * HDIM; }
    if (f1) { int p = s1 >> 16, j = s1 & 0xFFFF; r1 = (size_t)(poffs[p] + j) * HDIM; }
    const float* xrow = x + (size_t)token * HDIM;
    float* orow = out + (size_t)token * HDIM;
    #pragma unroll
    for (int c = 0; c < 4; c++) {
        int col = c * 256 + lane * 4;
        float4 xv = *(const float4*)(xrow + col);
        float4 o;
        if (f0) {
            uint2 u0 = *(const uint2*)(pcomp + r0 + col);
            float a0 = bf2f(u0.x & 0xFFFF), a1 = bf2f(u0.x >> 16);
            float a2 = bf2f(u0.y & 0xFFFF), a3 = bf2f(u0.y >> 16);
            if (f1) {
                uint2 u1 = *(const uint2*)(pcomp + r1 + col);
                a0 += bf2f(u1.x & 0xFFFF); a1 += bf2f(u1.x >> 16);
                a2 += bf2f(u1.y & 0xFFFF); a3 += bf2f(u1.y >> 16);
            }
            o.x = alpha * a0 + beta * xv.x;
            o.y = alpha * a1 + beta * xv.y;
            o.z = alpha * a2 + beta * xv.z;
            o.w = alpha * a3 + beta * xv.w;
        } else {
            o = xv;
        }
        *(float4*)(orow + col) = o;
    }
}

extern "C" void kernel_launch(void* const* d_in, const int* in_sizes, int n_in,
                              void* d_out, int out_size, void* d_ws, size_t ws_size,
                              hipStream_t stream) {
    const float* x   = (const float*)d_in[0];
    const float* gw1 = (const float*)d_in[1];
    const float* gb1 = (const float*)d_in[2];
    const float* gw2 = (const float*)d_in[3];
    const float* gb2 = (const float*)d_in[4];
    const float* pw  = (const float*)d_in[5];
    const float* pb  = (const float*)d_in[6];
    const float* prw = (const float*)d_in[7];
    const float* blend = (const float*)d_in[8];
    float* out = (float*)d_out;
    float* gate_out = out + (size_t)B_TOK * HDIM;

    char* w = (char*)d_ws;
    size_t o = 0;
    u16* xb      = (u16*)(w + o);   o += (size_t)B_TOK * HDIM * 2;
    u16* pathWT  = (u16*)(w + o);   o += (size_t)NPATH * HDIM * HDIM * 2;
    u16* projWT  = (u16*)(w + o);   o += (size_t)NPATH * HDIM * HDIM * 2;
    u16* w1hT    = (u16*)(w + o);   o += (size_t)HGATE * HDIM * 2;
    u16* w1lT    = (u16*)(w + o);   o += (size_t)HGATE * HDIM * 2;
    // hbuf (fp32, used until topk) overlaid with pcomp (bf16, written after topk)
    size_t uni = o;
    float* hbuf  = (float*)(w + uni);
    u16* pcomp   = (u16*)(w + uni);
    size_t hbuf_sz  = (size_t)B_TOK * HGATE * 4;
    size_t pcomp_sz = (size_t)MAXROWS * HDIM * 2;
    o += (hbuf_sz > pcomp_sz ? hbuf_sz : pcomp_sz);
    // xh/xl (f16 hi+residual of x, dead after gate GEMM) overlaid with hid (written by path1)
    size_t uni2 = o;
    u16* xh16    = (u16*)(w + uni2);                           // B_TOK*HDIM*2
    u16* xl16    = (u16*)(w + uni2 + (size_t)B_TOK * HDIM * 2); // B_TOK*HDIM*2
    u16* hid     = (u16*)(w + uni2);
    o += (size_t)MAXROWS * HDIM * 2;   // 69.2MB >= 2 * 33.6MB
    float* wnorm = (float*)(w + o); o += (size_t)B_TOK * NPATH * 4;
    int* tokens  = (int*)(w + o);   o += (size_t)NPATH * B_TOK * 4;
    uint32_t* slots = (uint32_t*)(w + o); o += (size_t)B_TOK * 2 * 4;
    int* counts  = (int*)(w + o);   o += 64;
    int* poffs   = (int*)(w + o);   o += 64;

    hipMemsetAsync(counts, 0, NPATH * sizeof(int), stream);
    k_convert_x<<<dim3((B_TOK * HDIM) / 1024), dim3(256), 0, stream>>>(x, xb, xh16, xl16);
    k_split_w1<<<dim3(HGATE / 32, HDIM / 32), dim3(32, 8), 0, stream>>>(gw1, w1hT, w1lT);
    k_transpose_bf16<<<dim3(32, 32, 8), dim3(32, 8), 0, stream>>>(pw, pathWT);
    k_transpose_bf16<<<dim3(32, 32, 8), dim3(32, 8), 0, stream>>>(prw, projWT);
    k_gate_mfma<<<dim3(B_TOK / 128, HGATE / 128), dim3(256), 0, stream>>>(
        xh16, xl16, w1hT, w1lT, gb1, hbuf);
    k_gate_topk<<<dim3(B_TOK / 64), dim3(256), 0, stream>>>(hbuf, gw2, gb2, gate_out,
                                                            wnorm, counts, tokens, slots);
    k_prefix<<<dim3(1), dim3(64), 0, stream>>>(counts, poffs);
    k_path1<<<dim3(128, 8, 8), dim3(256), 0, stream>>>(xb, pathWT, pb, hid,
                                                       counts, tokens, poffs);
    k_path2<<<dim3(128, 8, 8), dim3(256), 0, stream>>>(hid, projWT, wnorm, pcomp,
                                                       counts, tokens, poffs);
    k_blend2<<<dim3(B_TOK / 4), dim3(256), 0, stream>>>(x, pcomp, slots, poffs, blend, out);
}